// Round 9
// baseline (13380.510 us; speedup 1.0000x reference)
//
#include <hip/hip_runtime.h>
#include <cstdint>
#include <cstddef>

typedef __attribute__((ext_vector_type(4))) int int32x4;
typedef __attribute__((ext_vector_type(16))) int int32x16;

constexpr int M = 16384;
constexpr int N = 11008;
constexpr int K = 4096;
constexpr int BM = 256, BN = 256;
constexpr int NT_M = M / BM;                 // 64
constexpr int NT_N = N / BN;                 // 43
constexpr int NWG = NT_M * NT_N;             // 2752 = 8 * 344 (exact)
constexpr int NKC = K / 32;                  // 128 K-steps of 32

// ---- weight repack: int32 -> int8 in MFMA fragment order ----
// Bpk[nt][kc][cc][lane][16B]: lane l holds W[nt*256+cc*32+(l&31)]
//                                      [kc*32+(l>>5)*16 .. +15]
__global__ __launch_bounds__(256) void pack_w_kernel(const int* __restrict__ w32,
                                                     signed char* __restrict__ bpk) {
  const int tid = blockIdx.x * 256 + threadIdx.x;   // one 16B chunk each
  const int l = tid & 63;
  const int cc = (tid >> 6) & 7;
  const int kc = (tid >> 9) & 127;
  const int nt = tid >> 16;
  const int n = nt * 256 + cc * 32 + (l & 31);
  const int kb = kc * 32 + (l >> 5) * 16;
  const int* src = w32 + (size_t)n * K + kb;
  int32x4 o;
  #pragma unroll
  for (int c = 0; c < 4; ++c) {
    const int4 v = ((const int4*)src)[c];
    o[c] = (v.x & 255) | ((v.y & 255) << 8) |
           ((v.z & 255) << 16) | ((v.w & 255) << 24);
  }
  *(int32x4*)(bpk + (size_t)tid * 16) = o;
}

// ---- per-row symmetric int8 quantization of X, fragment-order output ----
// Apk[mt][kc][rc][lane][16B]: lane l holds X[mt*256+rc*32+(l&31)]
//                                      [kc*32+(l>>5)*16 .. +15]
__global__ __launch_bounds__(256) void quant_x_kernel(const float* __restrict__ x,
                                                      signed char* __restrict__ apk,
                                                      float* __restrict__ sx) {
  const int row = blockIdx.x;
  const int q = threadIdx.x;       // thread q: elements 16q .. 16q+15
  const float4* xr = (const float4*)(x + (size_t)row * K) + q * 4;
  float4 v[4];
  float amax = 0.f;
  #pragma unroll
  for (int c = 0; c < 4; ++c) {
    v[c] = xr[c];
    amax = fmaxf(amax, fmaxf(fmaxf(fabsf(v[c].x), fabsf(v[c].y)),
                             fmaxf(fabsf(v[c].z), fabsf(v[c].w))));
  }
  __shared__ float red[256];
  red[q] = amax;
  __syncthreads();
  #pragma unroll
  for (int s = 128; s >= 1; s >>= 1) {
    if (q < s) red[q] = fmaxf(red[q], red[q + s]);
    __syncthreads();
  }
  const float am = fmaxf(red[0], 1e-20f);
  const float inv = 127.f / am;
  if (q == 0) sx[row] = am * (1.f / 127.f);
  int32x4 o;
  #pragma unroll
  for (int c = 0; c < 4; ++c) {
    int q0 = min(127, max(-127, __float2int_rn(v[c].x * inv)));
    int q1 = min(127, max(-127, __float2int_rn(v[c].y * inv)));
    int q2 = min(127, max(-127, __float2int_rn(v[c].z * inv)));
    int q3 = min(127, max(-127, __float2int_rn(v[c].w * inv)));
    o[c] = (q0 & 255) | ((q1 & 255) << 8) | ((q2 & 255) << 16) | ((q3 & 255) << 24);
  }
  const int mt = row >> 8, rc = (row >> 5) & 7, lr = row & 31;
  const int kc = q >> 1, lk = q & 1;
  const size_t dst = ((size_t)(mt * 128 + kc) * 8 + rc) * 1024 + (lk * 32 + lr) * 16;
  *(int32x4*)(apk + dst) = o;
}

// ---- 256x256 int8 GEMM, NO LDS, NO BARRIERS (flatmm style) ----
// 8 waves (2x4), wave tile 128x64 (4x2 frags of 32x32, acc = 128 AGPR).
// Operands pre-packed in fragment order: per K=32 step a wave issues
// 6 global_load_dwordx4 (1 KB each, fully coalesced, exactly one MFMA
// operand) + 8 MFMA. 4 named register sets, depth-4 prefetch, counted
// vmcnt(18) -> ~1170 cyc lead > HBM latency. Reuse via L1/L2/L3
// (A chunk shared by 4 waves, B by 2; whole problem fits 256 MB LLC).
__global__ __launch_bounds__(512, 2) void gemm_i8_kernel(const signed char* __restrict__ apk,
                                                         const signed char* __restrict__ bpk,
                                                         const float* __restrict__ sx,
                                                         const float* __restrict__ sw,
                                                         float* __restrict__ out) {
  const int t = threadIdx.x;
  const int w = t >> 6;            // wave 0..7
  const int l = t & 63;

  // XCD-aware swizzle (bijective: 2752 % 8 == 0), nt-major tile order.
  const int bid = blockIdx.x;
  const int wg = (bid & 7) * (NWG / 8) + (bid >> 3);
  const int mt = wg & 63;
  const int nt = wg >> 6;

  const int wm = w >> 2, wn = w & 3; // wave tile (wm*128, wn*64) in block
  const signed char* pA = apk + ((size_t)(mt * 128) * 8 + wm * 4) * 1024 + l * 16;
  const signed char* pB = bpk + ((size_t)(nt * 128) * 8 + wn * 2) * 1024 + l * 16;

  int32x16 acc[4][2] = {};
  int32x4 s0a0, s0a1, s0a2, s0a3, s0b0, s0b1;
  int32x4 s1a0, s1a1, s1a2, s1a3, s1b0, s1b1;
  int32x4 s2a0, s2a1, s2a2, s2a3, s2b0, s2b1;
  int32x4 s3a0, s3a1, s3a2, s3a3, s3b0, s3b1;

#define MFMA_I8(a, b, c) __builtin_amdgcn_mfma_i32_32x32x32_i8(a, b, c, 0, 0, 0)

#define LOADS(S)                                                              \
  S##a0 = *(const int32x4*)(pA);                                              \
  S##a1 = *(const int32x4*)(pA + 1024);                                       \
  S##a2 = *(const int32x4*)(pA + 2048);                                       \
  S##a3 = *(const int32x4*)(pA + 3072);                                       \
  S##b0 = *(const int32x4*)(pB);                                              \
  S##b1 = *(const int32x4*)(pB + 1024);                                       \
  pA += 8192; pB += 8192;

#define MFMA8S(S)                                                             \
  __builtin_amdgcn_s_setprio(1);                                              \
  acc[0][0] = MFMA_I8(S##a0, S##b0, acc[0][0]);                               \
  acc[0][1] = MFMA_I8(S##a0, S##b1, acc[0][1]);                               \
  acc[1][0] = MFMA_I8(S##a1, S##b0, acc[1][0]);                               \
  acc[1][1] = MFMA_I8(S##a1, S##b1, acc[1][1]);                               \
  acc[2][0] = MFMA_I8(S##a2, S##b0, acc[2][0]);                               \
  acc[2][1] = MFMA_I8(S##a2, S##b1, acc[2][1]);                               \
  acc[3][0] = MFMA_I8(S##a3, S##b0, acc[3][0]);                               \
  acc[3][1] = MFMA_I8(S##a3, S##b1, acc[3][1]);                               \
  __builtin_amdgcn_s_setprio(0);

#define WAITV(n) asm volatile("s_waitcnt vmcnt(" #n ")" ::: "memory");
#define SB0() __builtin_amdgcn_sched_barrier(0);

  // Prologue: prefetch kc = 0..3 (24 loads outstanding).
  LOADS(s0) LOADS(s1) LOADS(s2) LOADS(s3)

  #pragma unroll 1
  for (int c = 0; c < 124; c += 4) {
    WAITV(18) SB0() MFMA8S(s0) SB0() LOADS(s0)   // consume kc=c,   load kc=c+4
    WAITV(18) SB0() MFMA8S(s1) SB0() LOADS(s1)   // consume kc=c+1, load kc=c+5
    WAITV(18) SB0() MFMA8S(s2) SB0() LOADS(s2)
    WAITV(18) SB0() MFMA8S(s3) SB0() LOADS(s3)
  }
  // Drain: kc = 124..127.
  WAITV(18) SB0() MFMA8S(s0)
  WAITV(12) SB0() MFMA8S(s1)
  WAITV(6)  SB0() MFMA8S(s2)
  WAITV(0)  SB0() MFMA8S(s3)

  // Epilogue: dequant + store.
  // 32x32 C/D map: col = lane&31, row = (r&3) + 8*(r>>2) + 4*(lane>>5).
  const int m0 = mt * BM, n0 = nt * BN;
  const int lk = l >> 5, lr = l & 31;
  const int rbase = lk * 4;
  float swv[2];
  #pragma unroll
  for (int fj = 0; fj < 2; ++fj) swv[fj] = sw[n0 + wn * 64 + fj * 32 + lr];
  #pragma unroll
  for (int fi = 0; fi < 4; ++fi) {
    #pragma unroll
    for (int r = 0; r < 16; ++r) {
      const int row = (r & 3) + 8 * (r >> 2) + rbase;
      const int grow = m0 + wm * 128 + fi * 32 + row;
      const float sxv = sx[grow];
      float* orow = out + (size_t)grow * N + n0 + wn * 64 + lr;
      #pragma unroll
      for (int fj = 0; fj < 2; ++fj) {
        orow[fj * 32] = (float)acc[fi][fj][r] * sxv * swv[fj];
      }
    }
  }
}

extern "C" void kernel_launch(void* const* d_in, const int* in_sizes, int n_in,
                              void* d_out, int out_size, void* d_ws, size_t ws_size,
                              hipStream_t stream) {
  const float* x = (const float*)d_in[0];
  const int* w32 = (const int*)d_in[1];
  const float* wscale = (const float*)d_in[2];
  float* out = (float*)d_out;

  // workspace: Apk[M*K] int8 | Bpk[N*K] int8 | sx[M] fp32  (~112 MB)
  signed char* apk = (signed char*)d_ws;
  signed char* bpk = apk + (size_t)M * K;
  float* sx = (float*)(bpk + (size_t)N * K);

  pack_w_kernel<<<N * K / 16 / 256, 256, 0, stream>>>(w32, bpk);
  quant_x_kernel<<<M, 256, 0, stream>>>(x, apk, sx);
  gemm_i8_kernel<<<NWG, 512, 0, stream>>>(apk, bpk, sx, wscale, out);
}

// Round 10
// 1181.997 us; speedup vs baseline: 11.3203x; 11.3203x over previous
//
#include <hip/hip_runtime.h>
#include <cstdint>
#include <cstddef>

typedef __attribute__((ext_vector_type(4))) int int32x4;
typedef __attribute__((ext_vector_type(16))) int int32x16;

#define DEVI __device__ __forceinline__

constexpr int M = 16384;
constexpr int N = 11008;
constexpr int K = 4096;
constexpr int BM = 256, BN = 256, BK = 64;   // BK in int8 elements (= bytes)
constexpr int NT_M = M / BM;                 // 64
constexpr int NT_N = N / BN;                 // 43
constexpr int NTILES = K / BK;               // 64
constexpr int NWG = NT_M * NT_N;             // 2752 = 8 * 344 (exact)
constexpr int SLOT = 32768;                  // 16 KB A + 16 KB B per ring slot

DEVI void gload_lds16(const void* gsrc, void* ldst) {
  __builtin_amdgcn_global_load_lds(
      (const __attribute__((address_space(1))) unsigned int*)gsrc,
      (__attribute__((address_space(3))) unsigned int*)ldst,
      16, 0, 0);
}

// ---- weight repack: int32 (harness int convention) -> int8 ----
__global__ __launch_bounds__(256) void pack_w_kernel(const int* __restrict__ w32,
                                                     signed char* __restrict__ w8) {
  const int idx = blockIdx.x * 256 + threadIdx.x;
  const int total4 = N * K / 4;
  if (idx < total4) {
    const int4 v = ((const int4*)w32)[idx];
    ((int*)w8)[idx] = (v.x & 255) | ((v.y & 255) << 8) |
                      ((v.z & 255) << 16) | ((v.w & 255) << 24);
  }
}

// ---- per-row symmetric int8 quantization of X ----
__global__ __launch_bounds__(256) void quant_x_kernel(const float* __restrict__ x,
                                                      signed char* __restrict__ xq,
                                                      float* __restrict__ sx) {
  const int row = blockIdx.x;
  const int t = threadIdx.x;
  const float4* xr = (const float4*)(x + (size_t)row * K);
  float4 v[4];
  float amax = 0.f;
  #pragma unroll
  for (int c = 0; c < 4; ++c) {
    v[c] = xr[c * 256 + t];
    amax = fmaxf(amax, fmaxf(fmaxf(fabsf(v[c].x), fabsf(v[c].y)),
                             fmaxf(fabsf(v[c].z), fabsf(v[c].w))));
  }
  __shared__ float red[256];
  red[t] = amax;
  __syncthreads();
  #pragma unroll
  for (int s = 128; s >= 1; s >>= 1) {
    if (t < s) red[t] = fmaxf(red[t], red[t + s]);
    __syncthreads();
  }
  const float am = fmaxf(red[0], 1e-20f);
  const float inv = 127.f / am;
  if (t == 0) sx[row] = am * (1.f / 127.f);
  int* xq32 = (int*)(xq + (size_t)row * K);
  #pragma unroll
  for (int c = 0; c < 4; ++c) {
    int q0 = min(127, max(-127, __float2int_rn(v[c].x * inv)));
    int q1 = min(127, max(-127, __float2int_rn(v[c].y * inv)));
    int q2 = min(127, max(-127, __float2int_rn(v[c].z * inv)));
    int q3 = min(127, max(-127, __float2int_rn(v[c].w * inv)));
    xq32[c * 256 + t] = (q0 & 255) | ((q1 & 255) << 8) |
                        ((q2 & 255) << 16) | ((q3 & 255) << 24);
  }
}

// ---- 256x256 int8 GEMM, 4 waves x 128x128 wave-tile, ring-4 LDS ----
// Key ratio change vs rounds 2-8: 16 MFMA per 8 ds_read_b128 per K-step
// per wave -> LDS demand 768 cyc/CU/tile vs MFMA 1171 cyc/SIMD/tile
// (was 1152 vs 1171 = co-limiting). acc = 256 regs; __launch_bounds__(256,1)
// gives the 512-reg budget (R4's spill was the (.,2) 256-reg cap).
// Schedule = round-6 reg-dbuf: reads of the next half-tile issue before the
// MFMA cluster consuming the previous one; counted lgkm(8); ring-4 counted
// vmcnt (certify-before-barrier); one barrier per K-tile.
// LDS slot: A 16 KB k-plane-major (plane*4096 + row*16), B 16 KB at +16384.
__global__ __launch_bounds__(256, 1) void gemm_i8_kernel(const signed char* __restrict__ aq,
                                                         const signed char* __restrict__ wq,
                                                         const float* __restrict__ sx,
                                                         const float* __restrict__ sw,
                                                         float* __restrict__ out) {
  __shared__ __align__(16) signed char smem[4 * SLOT];   // 128 KiB

  const int t = threadIdx.x;       // 0..255
  const int w = t >> 6;            // wave 0..3
  const int l = t & 63;

  // XCD-aware swizzle (bijective: 2752 % 8 == 0).
  const int bid = blockIdx.x;
  const int wg = (bid & 7) * (NWG / 8) + (bid >> 3);
  const int mt = wg / NT_N;
  const int nt = wg % NT_N;
  const int m0 = mt * BM, n0 = nt * BN;

  // Staging: thread t stages row t of A and row t of B, 4 k-planes each
  // (8 x 16B = 128 B/thread/tile). Dest = plane*4096 + w*1024 (+lane*16 HW).
  const signed char* srcA = aq + (size_t)(m0 + t) * K;
  const signed char* srcB = wq + (size_t)(n0 + t) * K;
  const int dBase = w * 1024;

#define STAGE(tile)                                                           \
  {                                                                           \
    signed char* sb = smem + ((tile) & 3) * SLOT;                             \
    const int ko = (tile) * BK;                                               \
    gload_lds16(srcA + ko,      sb + dBase);                                  \
    gload_lds16(srcA + ko + 16, sb + 4096 + dBase);                           \
    gload_lds16(srcA + ko + 32, sb + 8192 + dBase);                           \
    gload_lds16(srcA + ko + 48, sb + 12288 + dBase);                          \
    gload_lds16(srcB + ko,      sb + 16384 + dBase);                          \
    gload_lds16(srcB + ko + 16, sb + 20480 + dBase);                          \
    gload_lds16(srcB + ko + 32, sb + 24576 + dBase);                          \
    gload_lds16(srcB + ko + 48, sb + 28672 + dBase);                          \
  }

  // Wave output: 128x128 at (wm*128, wn*128); 4x4 frags of 32x32.
  const int wm = w >> 1, wn = w & 1;
  const int lk = l >> 5;           // 16B plane within k-step (0/1)
  const int lr = l & 31;
  int aOff[4], bOff[4];
  #pragma unroll
  for (int i = 0; i < 4; ++i)
    aOff[i] = lk * 4096 + (wm * 128 + i * 32 + lr) * 16;
  #pragma unroll
  for (int j = 0; j < 4; ++j)
    bOff[j] = 16384 + lk * 4096 + (wn * 128 + j * 32 + lr) * 16;

  int32x16 acc[4][4] = {};
  int32x4 af0[4], bf0[4], af1[4], bf1[4];

  // DSL(tile, ks): 8 ds_read_b128 for k-step ks (planes {2ks, 2ks+1}).
#define DSL(tile, ks, AF, BF)                                                 \
  {                                                                           \
    const signed char* sb = smem + ((tile) & 3) * SLOT + (ks) * 8192;         \
    AF[0] = *(const int32x4*)(sb + aOff[0]);                                  \
    AF[1] = *(const int32x4*)(sb + aOff[1]);                                  \
    AF[2] = *(const int32x4*)(sb + aOff[2]);                                  \
    AF[3] = *(const int32x4*)(sb + aOff[3]);                                  \
    BF[0] = *(const int32x4*)(sb + bOff[0]);                                  \
    BF[1] = *(const int32x4*)(sb + bOff[1]);                                  \
    BF[2] = *(const int32x4*)(sb + bOff[2]);                                  \
    BF[3] = *(const int32x4*)(sb + bOff[3]);                                  \
  }

#define MFMA16(AF, BF)                                                        \
  __builtin_amdgcn_s_setprio(1);                                              \
  {                                                                           \
    _Pragma("unroll")                                                         \
    for (int i = 0; i < 4; ++i) {                                             \
      _Pragma("unroll")                                                       \
      for (int j = 0; j < 4; ++j) {                                           \
        acc[i][j] = __builtin_amdgcn_mfma_i32_32x32x32_i8(AF[i], BF[j],       \
                                                          acc[i][j], 0, 0, 0);\
      }                                                                       \
    }                                                                         \
  }                                                                           \
  __builtin_amdgcn_s_setprio(0);

#define WAITV(n) asm volatile("s_waitcnt vmcnt(" #n ")" ::: "memory");
#define WLGKM(n)                                                              \
  asm volatile("s_waitcnt lgkmcnt(" #n ")" ::: "memory");                     \
  __builtin_amdgcn_sched_barrier(0);
#define BAR() __builtin_amdgcn_s_barrier();

  // Steady state: entering iter tt, 16 vm-loads in flight (tiles tt+1, tt+2);
  // set0 holds Read(tt.0) (issued last iter, possibly in flight).
#define ITER(tt)                                                              \
  WAITV(8)                  /* certify tile tt+1 (oldest 8) */                 \
  BAR()                     /* publish tt+1; all reads of tt-1 retired */      \
  STAGE(tt + 3)             /* overwrite slot (tt-1)&3 — safe after BAR */    \
  DSL(tt, 1, af1, bf1)      /* Read(tt.1) -> set1 */                           \
  WLGKM(8)                  /* Read(tt.0) complete; set1 in flight */          \
  MFMA16(af0, bf0)          /* tile tt, k-step 0 (586 cyc cover) */            \
  DSL(tt + 1, 0, af0, bf0)  /* Read(tt+1.0) -> set0 */                         \
  WLGKM(8)                  /* Read(tt.1) complete; set0 in flight */          \
  MFMA16(af1, bf1)          /* tile tt, k-step 1 */

  // Prologue: stage tiles 0..2 (24 loads); certify tile 0; first reads.
  STAGE(0) STAGE(1) STAGE(2)
  WAITV(16)
  BAR()
  DSL(0, 0, af0, bf0)

  #pragma unroll 4
  for (int tt = 0; tt < 60; ++tt) {
    ITER(tt)
  }
  ITER(60)   // stages tile 63 (last)
  // tt = 61: tiles 62,63 in flight (16) -> certify 62
  WAITV(8) BAR()
  DSL(61, 1, af1, bf1) WLGKM(8) MFMA16(af0, bf0)
  DSL(62, 0, af0, bf0) WLGKM(8) MFMA16(af1, bf1)
  // tt = 62: certify 63
  WAITV(0) BAR()
  DSL(62, 1, af1, bf1) WLGKM(8) MFMA16(af0, bf0)
  DSL(63, 0, af0, bf0) WLGKM(8) MFMA16(af1, bf1)
  // tt = 63
  DSL(63, 1, af1, bf1) WLGKM(8) MFMA16(af0, bf0)
  WLGKM(0) MFMA16(af1, bf1)

  // Epilogue: dequant + store.
  // 32x32 C/D map: col = lane&31, row = (r&3) + 8*(r>>2) + 4*(lane>>5).
  const int rbase = lk * 4;
  float swv[4];
  #pragma unroll
  for (int fj = 0; fj < 4; ++fj) swv[fj] = sw[n0 + wn * 128 + fj * 32 + lr];
  #pragma unroll
  for (int fi = 0; fi < 4; ++fi) {
    #pragma unroll
    for (int r = 0; r < 16; ++r) {
      const int row = (r & 3) + 8 * (r >> 2) + rbase;
      const int grow = m0 + wm * 128 + fi * 32 + row;
      const float sxv = sx[grow];
      float* orow = out + (size_t)grow * N + n0 + wn * 128 + lr;
      #pragma unroll
      for (int fj = 0; fj < 4; ++fj) {
        orow[fj * 32] = (float)acc[fi][fj][r] * sxv * swv[fj];
      }
    }
  }
}

extern "C" void kernel_launch(void* const* d_in, const int* in_sizes, int n_in,
                              void* d_out, int out_size, void* d_ws, size_t ws_size,
                              hipStream_t stream) {
  const float* x = (const float*)d_in[0];
  const int* w32 = (const int*)d_in[1];
  const float* wscale = (const float*)d_in[2];
  float* out = (float*)d_out;

  signed char* xq = (signed char*)d_ws;
  signed char* wq = xq + (size_t)M * K;
  float* sx = (float*)(wq + (size_t)N * K);

  pack_w_kernel<<<(N * K / 4 + 255) / 256, 256, 0, stream>>>(w32, wq);
  quant_x_kernel<<<M, 256, 0, stream>>>(x, xq, sx);
  gemm_i8_kernel<<<NWG, 256, 0, stream>>>(xq, wq, sx, wscale, out);
}